// Round 10
// baseline (169.990 us; speedup 1.0000x reference)
//
#include <hip/hip_runtime.h>
#include <hip/hip_bf16.h>

// b=4, dim=512, hidden=512, heads=8, dim_head=64, L=2048.
// Q is pre-scaled by 1/8 * log2(e) so softmax uses native v_exp_f32 (exp2).
#define B 4
#define DIM 512
#define HID 512
#define NH 8
#define DH 64
#define L 2048
#define QSCALE (0.125f * 1.4426950408889634f)

typedef __attribute__((ext_vector_type(8)))  short bf16x8;   // 8 bf16 (4 VGPRs)
typedef __attribute__((ext_vector_type(4)))  float f32x4;    // 16x16 MFMA acc
typedef __attribute__((ext_vector_type(16))) float f32x16;   // 32x32 MFMA acc
typedef __attribute__((ext_vector_type(4)))  int   i32x4;

static __device__ __forceinline__ short f32_to_bf16s(float f) {
    __hip_bfloat16 h = __float2bfloat16(f);
    return *reinterpret_cast<short*>(&h);
}
static __device__ __forceinline__ float bf16s_to_f32(short s) {
    return __uint_as_float(((unsigned)(unsigned short)s) << 16);
}

// Raw v_exp_f32 (2^x) — libm exp2f w/o fast-math is multi-instr (R8 lesson).
static __device__ __forceinline__ float fast_exp2(float x) {
    float r;
    asm("v_exp_f32 %0, %1" : "=v"(r) : "v"(x));
    return r;
}

// async 16B global->LDS DMA: LDS dest = uniform base + lane*16
static __device__ __forceinline__ void gl_lds16(const short* g, short* l) {
    __builtin_amdgcn_global_load_lds(
        (const __attribute__((address_space(1))) void*)g,
        (__attribute__((address_space(3))) void*)l, 16, 0, 0);
}

// XOR-8-swizzled 16B fragment read from a [rows][64-short] LDS tile.
static __device__ __forceinline__ bf16x8 lds_frag(const short* t, int row, int c) {
    bf16x8 v;
    __builtin_memcpy(&v, t + row * 64 + ((c ^ (row & 7)) * 8), 16);
    return v;
}

// sigma-permuted V fragment: chunks c0,c0+1 with sub-offset me4 (0/4 shorts).
// Matches the PV B-frag built directly from the S^T C-layout dwords.
static __device__ __forceinline__ bf16x8 lds_vfrag(const short* t, int row,
                                                   int c0, int me4) {
    int2 a, b;
    __builtin_memcpy(&a, t + row * 64 + ((c0 ^ (row & 7)) * 8 + me4), 8);
    __builtin_memcpy(&b, t + row * 64 + (((c0 + 1) ^ (row & 7)) * 8 + me4), 8);
    i32x4 v = {a.x, a.y, b.x, b.y};
    return __builtin_bit_cast(bf16x8, v);
}

// ---------------------------------------------------------------------------
// prep: fused weight-cast (blocks 0..1023) + x transpose (blocks 1024..2047).
// ---------------------------------------------------------------------------
__global__ __launch_bounds__(256) void prep(
    const float* __restrict__ wq, const float* __restrict__ wo,
    short* __restrict__ wdst,
    const float* __restrict__ X, short* __restrict__ XT)
{
    const int bx  = blockIdx.x;
    const int tid = threadIdx.x;
    if (bx < 1024) {
        const int i = (bx * 256 + tid) * 4;
        float4 v;
        if (i < 786432) v = *(const float4*)(wq + i);
        else            v = *(const float4*)(wo + (i - 786432));
        short4 pk = {f32_to_bf16s(v.x), f32_to_bf16s(v.y),
                     f32_to_bf16s(v.z), f32_to_bf16s(v.w)};
        *(short4*)(wdst + i) = pk;
        return;
    }
    const int bid = bx - 1024;
    const int l0 = (bid & 31) * 64;
    const int c0 = ((bid >> 5) & 7) * 64;
    const int b  = bid >> 8;

    __shared__ float tile[64][65];
    const float* Xb = X + (size_t)b * DIM * L;

    #pragma unroll
    for (int it = 0; it < 16; ++it) {
        const int cr = (tid >> 6) + it * 4;
        const int lc = tid & 63;
        tile[cr][lc] = Xb[(size_t)(c0 + cr) * L + l0 + lc];
    }
    __syncthreads();
    short* XTb = XT + (size_t)b * L * DIM;
    #pragma unroll
    for (int it = 0; it < 8; ++it) {
        const int l  = (tid >> 5) + it * 8;
        const int c2 = (tid & 31) * 2;
        short2 pk = {f32_to_bf16s(tile[c2][l]), f32_to_bf16s(tile[c2 + 1][l])};
        *(short2*)(XTb + (size_t)(l0 + l) * DIM + c0 + c2) = pk;
    }
}

// ---------------------------------------------------------------------------
// qkv_mfma: 128o x 128l tile, BK=64, LDS-staged (m97 structure + XOR swizzle).
// ---------------------------------------------------------------------------
__global__ __launch_bounds__(256) void qkv_mfma(
    const short* __restrict__ Wb, const short* __restrict__ XT,
    const float* __restrict__ bias,
    short* __restrict__ qws, short* __restrict__ kws, short* __restrict__ vws)
{
    const int lBase = blockIdx.x * 128;
    const int oBase = blockIdx.y * 128;
    const int b     = blockIdx.z;
    const int tid   = threadIdx.x;
    const int wave  = tid >> 6;
    const int lane  = tid & 63;
    const int lid   = lane & 15;
    const int quad  = lane >> 4;
    const int rsub  = lane >> 3;
    const int cl    = (lane & 7) ^ rsub;

    __shared__ __align__(16) short Wt[128 * 64];
    __shared__ __align__(16) short Xt[128 * 64];

    const short* XTb = XT + (size_t)b * L * DIM;
    const int oLoc = (wave & 1) * 64;
    const int lLoc = (wave >> 1) * 64;

    f32x4 acc[4][4];
    #pragma unroll
    for (int mi = 0; mi < 4; ++mi)
        #pragma unroll
        for (int ni = 0; ni < 4; ++ni) acc[mi][ni] = (f32x4){0.f, 0.f, 0.f, 0.f};

    for (int c0 = 0; c0 < DIM; c0 += 64) {
        if (c0) __syncthreads();
        #pragma unroll
        for (int t = 0; t < 4; ++t) {
            const int ch = wave * 4 + t;
            const int r  = ch * 8 + rsub;
            gl_lds16(Wb  + (size_t)(oBase + r) * DIM + c0 + cl * 8, Wt + ch * 512);
            gl_lds16(XTb + (size_t)(lBase + r) * DIM + c0 + cl * 8, Xt + ch * 512);
        }
        __syncthreads();
        #pragma unroll
        for (int kc = 0; kc < 2; ++kc) {
            bf16x8 a[4], bb[4];
            #pragma unroll
            for (int mi = 0; mi < 4; ++mi)
                a[mi] = lds_frag(Wt, oLoc + mi * 16 + lid, kc * 4 + quad);
            #pragma unroll
            for (int ni = 0; ni < 4; ++ni)
                bb[ni] = lds_frag(Xt, lLoc + ni * 16 + lid, kc * 4 + quad);
            #pragma unroll
            for (int mi = 0; mi < 4; ++mi)
                #pragma unroll
                for (int ni = 0; ni < 4; ++ni)
                    acc[mi][ni] = __builtin_amdgcn_mfma_f32_16x16x32_bf16(
                        a[mi], bb[ni], acc[mi][ni], 0, 0, 0);
        }
    }

    const int rty = oBase >> 9;
    const float sc = (rty == 0) ? QSCALE : 1.0f;
    const int h = ((oBase + oLoc) >> 6) & 7;

    #pragma unroll
    for (int mi = 0; mi < 4; ++mi) {
        const int dB = mi * 16 + quad * 4;
        float bia[4];
        #pragma unroll
        for (int r = 0; r < 4; ++r)
            bia[r] = bias[oBase + oLoc + mi * 16 + quad * 4 + r];

        if (rty < 2) {
            short* dst = (rty == 0 ? qws : kws) + (((size_t)b * NH + h) * L) * DH;
            #pragma unroll
            for (int ni = 0; ni < 4; ++ni) {
                const int l = lBase + lLoc + ni * 16 + lid;
                short4 pk = {f32_to_bf16s((acc[mi][ni][0] + bia[0]) * sc),
                             f32_to_bf16s((acc[mi][ni][1] + bia[1]) * sc),
                             f32_to_bf16s((acc[mi][ni][2] + bia[2]) * sc),
                             f32_to_bf16s((acc[mi][ni][3] + bia[3]) * sc)};
                *(short4*)(dst + (size_t)l * DH + dB) = pk;
            }
        } else {
            short* dst = vws + (((size_t)b * NH + h) * DH) * L;
            #pragma unroll
            for (int r = 0; r < 4; ++r) {
                const int d = dB + r;
                #pragma unroll
                for (int ni = 0; ni < 4; ++ni)
                    dst[(size_t)d * L + lBase + lLoc + ni * 16 + lid] =
                        f32_to_bf16s((acc[mi][ni][r] + bia[r]) * sc);
            }
        }
    }
}

// ---------------------------------------------------------------------------
// attn_mfma: 32x32x16 transposed-S attention, EXTERNAL split-j x4.
// R10: sigma-permuted PV layout (PV B-frag = S^T C-layout dwords directly,
// no lane exchange); lsum via ones-MFMA row-sum (no extract/add VALU, no
// final shuffle); XCD-local grid (iTile in blockIdx.z).
// ---------------------------------------------------------------------------
__global__ __launch_bounds__(256) void attn_mfma(
    const short* __restrict__ Q, const short* __restrict__ K,
    const short* __restrict__ VT,
    short* __restrict__ Op0, short* __restrict__ Op1,
    short* __restrict__ Op2, short* __restrict__ Op3,
    float* __restrict__ Lp)
{
    const int h     = blockIdx.x >> 2;     // 0..7
    const int qtr   = blockIdx.x & 3;      // j-quarter
    const int b     = blockIdx.y;
    const int iTile = blockIdx.z;          // 0..15 — stride-128 linear id =>
                                           // all 16 iTiles of one (b,h,qtr)
                                           // land on the same XCD (K/V L2 reuse)
    const int tid   = threadIdx.x;
    const int wave  = tid >> 6;            // 0..3 (q-subtile)
    const int lane  = tid & 63;
    const int l5    = lane & 31;           // query col / A-frag row
    const int me    = lane >> 5;           // k-half within frags
    const int me4   = me * 4;
    const int rsub  = lane >> 3;
    const int cl    = (lane & 7) ^ rsub;

    short* __restrict__ Op = (qtr & 2) ? ((qtr & 1) ? Op3 : Op2)
                                       : ((qtr & 1) ? Op1 : Op0);
    float* __restrict__ Lq = Lp + (size_t)qtr * (B * NH * L);

    const size_t headOff = ((size_t)b * NH + h) * (size_t)L * DH;
    const short* Qh = Q + headOff;    // [l][d]
    const short* Kh = K + headOff;    // [l][d]
    const short* Vh = VT + headOff;   // [d][l]

    __shared__ __align__(16) short Kt[64 * 64];   // 8 KB, rows = key j
    __shared__ __align__(16) short Vt[64 * 64];   // 8 KB, rows = dim d

    // Q B-fragments (col n = query = l5, k = d = kc*16 + me*8 + i), in regs
    const int q0 = iTile * 128 + wave * 32;
    bf16x8 qf[4];
    #pragma unroll
    for (int kc = 0; kc < 4; ++kc)
        qf[kc] = *(const bf16x8*)(Qh + (size_t)(q0 + l5) * DH + kc * 16 + me4 * 2);

    // ones A-frag for the row-sum MFMA (bf16 1.0 pairs)
    const i32x4 onesI = {0x3F803F80, 0x3F803F80, 0x3F803F80, 0x3F803F80};
    const bf16x8 ones = __builtin_bit_cast(bf16x8, onesI);

    f32x16 oacc[2], lacc;
    #pragma unroll
    for (int dt = 0; dt < 2; ++dt)
        #pragma unroll
        for (int r = 0; r < 16; ++r) oacc[dt][r] = 0.f;
    #pragma unroll
    for (int r = 0; r < 16; ++r) lacc[r] = 0.f;

    const int jt0 = qtr * 8;
    for (int it = 0; it < 8; ++it) {
        const int j0 = (jt0 + it) * 64;
        if (it) __syncthreads();
        #pragma unroll
        for (int t = 0; t < 2; ++t) {
            const int ch = wave * 2 + t;
            const int r  = ch * 8 + rsub;
            gl_lds16(Kh + (size_t)(j0 + r) * DH + cl * 8, Kt + ch * 512);
            gl_lds16(Vh + (size_t)r * L + j0 + cl * 8,    Vt + ch * 512);
        }
        __syncthreads();

        // ---- per 32-key m-tile: S^T, exp2 + perm-pack -> dw (C-layout dwords)
        // dw[mt][g][p] packs S^T regs (4g+2p, 4g+2p+1): local j = 8g+4me+2p(+1)
        unsigned dw[2][4][2];
        #pragma unroll
        for (int mt = 0; mt < 2; ++mt) {
            f32x16 s;
            #pragma unroll
            for (int r = 0; r < 16; ++r) s[r] = 0.f;
            #pragma unroll
            for (int kc = 0; kc < 4; ++kc) {
                bf16x8 a = lds_frag(Kt, mt * 32 + l5, kc * 2 + me);
                s = __builtin_amdgcn_mfma_f32_32x32x16_bf16(a, qf[kc], s, 0, 0, 0);
            }
            #pragma unroll
            for (int g = 0; g < 4; ++g) {
                #pragma unroll
                for (int p = 0; p < 2; ++p) {
                    const float p0 = fast_exp2(s[4 * g + 2 * p]);
                    const float p1 = fast_exp2(s[4 * g + 2 * p + 1]);
                    dw[mt][g][p] = __builtin_amdgcn_perm(
                        __float_as_uint(p1), __float_as_uint(p0), 0x07060302u);
                }
            }
        }

        // ---- PV with sigma-permuted k-mapping: B-frag = own dwords, no exchange.
        // k = me*8+i maps to local j = 16kl + 8*(i>>2) + 4me + (i&3); the V
        // A-frag loads the matching columns (lds_vfrag). lacc row-sums P.
        #pragma unroll
        for (int mt = 0; mt < 2; ++mt) {
            #pragma unroll
            for (int kl = 0; kl < 2; ++kl) {
                i32x4 bi = {(int)dw[mt][2 * kl][0], (int)dw[mt][2 * kl][1],
                            (int)dw[mt][2 * kl + 1][0], (int)dw[mt][2 * kl + 1][1]};
                bf16x8 pb = __builtin_bit_cast(bf16x8, bi);
                lacc = __builtin_amdgcn_mfma_f32_32x32x16_bf16(ones, pb, lacc, 0, 0, 0);
                const int c0 = mt * 4 + kl * 2;
                #pragma unroll
                for (int dt = 0; dt < 2; ++dt) {
                    bf16x8 a = lds_vfrag(Vt, dt * 32 + l5, c0, me4);
                    oacc[dt] = __builtin_amdgcn_mfma_f32_32x32x16_bf16(a, pb, oacc[dt], 0, 0, 0);
                }
            }
        }
    }

    // ---- lacc: every reg holds lsum(query = q0+l5) (full k-sum in-MFMA)
    const float vh = lacc[0];
    const int qg = q0 + l5;
    if (me == 0)
        Lq[((size_t)b * NH + h) * L + qg] = vh;

    // ---- normalized partial o_p = O_p / l_p -> bf16 [b][l][h*64+d]
    const float inv = 1.0f / vh;
    short* ab = Op + ((size_t)b * L + qg) * HID + h * DH;
    #pragma unroll
    for (int dt = 0; dt < 2; ++dt) {
        #pragma unroll
        for (int g = 0; g < 4; ++g) {
            const int d = dt * 32 + 8 * g + me4;
            short4 pk = {f32_to_bf16s(oacc[dt][4 * g]     * inv),
                         f32_to_bf16s(oacc[dt][4 * g + 1] * inv),
                         f32_to_bf16s(oacc[dt][4 * g + 2] * inv),
                         f32_to_bf16s(oacc[dt][4 * g + 3] * inv)};
            *(short4*)(ab + d) = pk;
        }
    }
}

// ---------------------------------------------------------------------------
// combine4: Abf[b][l][c] = sum_i(l_i * o_i) / sum_i(l_i), bf16 out.
// ---------------------------------------------------------------------------
__global__ __launch_bounds__(256) void combine4(
    const short* __restrict__ O0, const short* __restrict__ O1,
    const short* __restrict__ O2, const short* __restrict__ O3,
    const float* __restrict__ Lp, short* __restrict__ Abf)
{
    const int g = blockIdx.x * 256 + threadIdx.x;
    const int i = g * 4;
    const int b = i >> 20;
    const int rem = i & 1048575;
    const int l = rem >> 9;
    const int c = rem & 511;
    const int h = c >> 6;
    const size_t li = ((size_t)b * NH + h) * L + l;
    const float w0 = Lp[li];
    const float w1 = Lp[li + (size_t)B * NH * L];
    const float w2 = Lp[li + (size_t)2 * B * NH * L];
    const float w3 = Lp[li + (size_t)3 * B * NH * L];
    const float inv = 1.0f / (w0 + w1 + w2 + w3);
    const short4 a = *(const short4*)(O0 + i);
    const short4 bb = *(const short4*)(O1 + i);
    const short4 cc = *(const short4*)(O2 + i);
    const short4 dd = *(const short4*)(O3 + i);
    short4 pk = {
        f32_to_bf16s((w0 * bf16s_to_f32(a.x) + w1 * bf16s_to_f32(bb.x) +
                      w2 * bf16s_to_f32(cc.x) + w3 * bf16s_to_f32(dd.x)) * inv),
        f32_to_bf16s((w0 * bf16s_to_f32(a.y) + w1 * bf16s_to_f32(bb.y) +
                      w2 * bf16s_to_f32(cc.y) + w3 * bf16s_to_f32(dd.y)) * inv),
        f32_to_bf16s((w0 * bf16s_to_f32(a.z) + w1 * bf16s_to_f32(bb.z) +
                      w2 * bf16s_to_f32(cc.z) + w3 * bf16s_to_f32(dd.z)) * inv),
        f32_to_bf16s((w0 * bf16s_to_f32(a.w) + w1 * bf16s_to_f32(bb.w) +
                      w2 * bf16s_to_f32(cc.w) + w3 * bf16s_to_f32(dd.w)) * inv)};
    *(short4*)(Abf + i) = pk;
}

// ---------------------------------------------------------------------------
// out_mfma: 64o x 128l tile, BK=64, LDS-staged.
// ---------------------------------------------------------------------------
__global__ __launch_bounds__(256) void out_mfma(
    const short* __restrict__ Wo, const short* __restrict__ Abf,
    const float* __restrict__ bias, float* __restrict__ out)
{
    const int lBase = blockIdx.x * 128;
    const int oBase = blockIdx.y * 64;
    const int b     = blockIdx.z;
    const int tid   = threadIdx.x;
    const int wave  = tid >> 6;
    const int lane  = tid & 63;
    const int lid   = lane & 15;
    const int quad  = lane >> 4;
    const int rsub  = lane >> 3;
    const int cl    = (lane & 7) ^ rsub;

    __shared__ __align__(16) short Wt[64 * 64];
    __shared__ __align__(16) short At[128 * 64];

    const short* Ab = Abf + (size_t)b * L * HID;
    const int oLoc = (wave & 1) * 32;
    const int lLoc = (wave >> 1) * 64;

    f32x4 acc[2][4];
    #pragma unroll
    for (int mi = 0; mi < 2; ++mi)
        #pragma unroll
        for (int ni = 0; ni < 4; ++ni) acc[mi][ni] = (f32x4){0.f, 0.f, 0.f, 0.f};

    for (int c0 = 0; c0 < HID; c0 += 64) {
        if (c0) __syncthreads();
        #pragma unroll
        for (int t = 0; t < 2; ++t) {
            const int ch = wave * 2 + t;
            const int r  = ch * 8 + rsub;
            gl_lds16(Wo + (size_t)(oBase + r) * HID + c0 + cl * 8, Wt + ch * 512);
        }
        #pragma unroll
        for (int t = 0; t < 4; ++t) {
            const int ch = wave * 4 + t;
            const int r  = ch * 8 + rsub;
            gl_lds16(Ab + (size_t)(lBase + r) * HID + c0 + cl * 8, At + ch * 512);
        }
        __syncthreads();
        #pragma unroll
        for (int kc = 0; kc < 2; ++kc) {
            bf16x8 a[2], bb[4];
            #pragma unroll
            for (int mi = 0; mi < 2; ++mi)
                a[mi] = lds_frag(Wt, oLoc + mi * 16 + lid, kc * 4 + quad);
            #pragma unroll
            for (int ni = 0; ni < 4; ++ni)
                bb[ni] = lds_frag(At, lLoc + ni * 16 + lid, kc * 4 + quad);
            #pragma unroll
            for (int mi = 0; mi < 2; ++mi)
                #pragma unroll
                for (int ni = 0; ni < 4; ++ni)
                    acc[mi][ni] = __builtin_amdgcn_mfma_f32_16x16x32_bf16(
                        a[mi], bb[ni], acc[mi][ni], 0, 0, 0);
        }
    }

    #pragma unroll
    for (int mi = 0; mi < 2; ++mi) {
        #pragma unroll
        for (int r = 0; r < 4; ++r) {
            const int o = oBase + oLoc + mi * 16 + quad * 4 + r;
            const float bia = bias[o];
            #pragma unroll
            for (int ni = 0; ni < 4; ++ni)
                out[((size_t)b * DIM + o) * L + lBase + lLoc + ni * 16 + lid] =
                    acc[mi][ni][r] + bia;
        }
    }
}

// ---------------------------------------------------------------------------
extern "C" void kernel_launch(void* const* d_in, const int* in_sizes, int n_in,
                              void* d_out, int out_size, void* d_ws, size_t ws_size,
                              hipStream_t stream)
{
    const float* x     = (const float*)d_in[0];
    const float* w_qkv = (const float*)d_in[1];
    const float* b_qkv = (const float*)d_in[2];
    const float* w_out = (const float*)d_in[3];
    const float* b_out = (const float*)d_in[4];
    float* out = (float*)d_out;

    char* w = (char*)d_ws;
    short* xT  = (short*)(w);                    //  8 MB  bf16 [b][l][c]  (dead after qkv)
    short* wqb = (short*)(w + (8u << 20));       //  1.5 MB
    short* wob = wqb + 786432;                   //  0.5 MB
    short* qws = (short*)(w + (10u << 20));      //  8 MB  [b][h][l][d]
    short* kws = (short*)(w + (18u << 20));      //  8 MB  [b][h][l][d]
    short* vws = (short*)(w + (26u << 20));      //  8 MB  [b][h][d][l]
    short* Abf = (short*)(w + (34u << 20));      //  8 MB  [b][l][hid]
    short* Op1 = (short*)(w);                    //  8 MB  (reuses dead xT)
    short* Op2 = (short*)(w + (42u << 20));      //  8 MB
    short* Op3 = (short*)(w + (50u << 20));      //  8 MB
    float* Lp  = (float*)(w + (58u << 20));      //  1 MB  (4 x [b][h][l])
    short* Op0 = (short*)d_out;                  //  8 MB of d_out (scratch)

    dim3 blk(256);
    prep<<<dim3(2048), blk, 0, stream>>>(w_qkv, w_out, wqb, x, xT);
    qkv_mfma<<<dim3(L / 128, 1536 / 128, B), blk, 0, stream>>>(
        wqb, xT, b_qkv, qws, kws, vws);
    attn_mfma<<<dim3(NH * 4, B, L / 128), blk, 0, stream>>>(
        qws, kws, vws, Op0, Op1, Op2, Op3, Lp);
    combine4<<<dim3(4096), blk, 0, stream>>>(Op0, Op1, Op2, Op3, Lp, Abf);
    out_mfma<<<dim3(L / 128, DIM / 64, B), blk, 0, stream>>>(
        wob, Abf, b_out, out);
}

// Round 11
// 161.888 us; speedup vs baseline: 1.0500x; 1.0500x over previous
//
#include <hip/hip_runtime.h>
#include <hip/hip_bf16.h>

// b=4, dim=512, hidden=512, heads=8, dim_head=64, L=2048.
// Q is pre-scaled by 1/8 * log2(e) so softmax uses native v_exp_f32 (exp2).
#define B 4
#define DIM 512
#define HID 512
#define NH 8
#define DH 64
#define L 2048
#define QSCALE (0.125f * 1.4426950408889634f)

typedef __attribute__((ext_vector_type(8)))  short bf16x8;   // 8 bf16 (4 VGPRs)
typedef __attribute__((ext_vector_type(4)))  float f32x4;    // 16x16 MFMA acc
typedef __attribute__((ext_vector_type(16))) float f32x16;   // 32x32 MFMA acc
typedef __attribute__((ext_vector_type(4)))  int   i32x4;

static __device__ __forceinline__ short f32_to_bf16s(float f) {
    __hip_bfloat16 h = __float2bfloat16(f);
    return *reinterpret_cast<short*>(&h);
}
static __device__ __forceinline__ float bf16s_to_f32(short s) {
    return __uint_as_float(((unsigned)(unsigned short)s) << 16);
}

// Raw v_exp_f32 (2^x) — libm exp2f w/o fast-math is multi-instr (R8 lesson).
static __device__ __forceinline__ float fast_exp2(float x) {
    float r;
    asm("v_exp_f32 %0, %1" : "=v"(r) : "v"(x));
    return r;
}

// async 16B global->LDS DMA: LDS dest = uniform base + lane*16
static __device__ __forceinline__ void gl_lds16(const short* g, short* l) {
    __builtin_amdgcn_global_load_lds(
        (const __attribute__((address_space(1))) void*)g,
        (__attribute__((address_space(3))) void*)l, 16, 0, 0);
}

// XOR-8-swizzled 16B fragment read from a [rows][64-short] LDS tile.
static __device__ __forceinline__ bf16x8 lds_frag(const short* t, int row, int c) {
    bf16x8 v;
    __builtin_memcpy(&v, t + row * 64 + ((c ^ (row & 7)) * 8), 16);
    return v;
}

// ---------------------------------------------------------------------------
// prep: fused weight-cast (blocks 0..1023) + x transpose (blocks 1024..2047).
// ---------------------------------------------------------------------------
__global__ __launch_bounds__(256) void prep(
    const float* __restrict__ wq, const float* __restrict__ wo,
    short* __restrict__ wdst,
    const float* __restrict__ X, short* __restrict__ XT)
{
    const int bx  = blockIdx.x;
    const int tid = threadIdx.x;
    if (bx < 1024) {
        const int i = (bx * 256 + tid) * 4;
        float4 v;
        if (i < 786432) v = *(const float4*)(wq + i);
        else            v = *(const float4*)(wo + (i - 786432));
        short4 pk = {f32_to_bf16s(v.x), f32_to_bf16s(v.y),
                     f32_to_bf16s(v.z), f32_to_bf16s(v.w)};
        *(short4*)(wdst + i) = pk;
        return;
    }
    const int bid = bx - 1024;
    const int l0 = (bid & 31) * 64;
    const int c0 = ((bid >> 5) & 7) * 64;
    const int b  = bid >> 8;

    __shared__ float tile[64][65];
    const float* Xb = X + (size_t)b * DIM * L;

    #pragma unroll
    for (int it = 0; it < 16; ++it) {
        const int cr = (tid >> 6) + it * 4;
        const int lc = tid & 63;
        tile[cr][lc] = Xb[(size_t)(c0 + cr) * L + l0 + lc];
    }
    __syncthreads();
    short* XTb = XT + (size_t)b * L * DIM;
    #pragma unroll
    for (int it = 0; it < 8; ++it) {
        const int l  = (tid >> 5) + it * 8;
        const int c2 = (tid & 31) * 2;
        short2 pk = {f32_to_bf16s(tile[c2][l]), f32_to_bf16s(tile[c2 + 1][l])};
        *(short2*)(XTb + (size_t)(l0 + l) * DIM + c0 + c2) = pk;
    }
}

// ---------------------------------------------------------------------------
// qkv_mfma: 128o x 128l tile, BK=64, LDS-staged (m97 structure + XOR swizzle).
// V is stored with sigma-permuted key columns (bits 2<->3 of the within-16
// index) so attention's PV A-fragment is a single swizzled b128 LDS read.
// ---------------------------------------------------------------------------
__global__ __launch_bounds__(256) void qkv_mfma(
    const short* __restrict__ Wb, const short* __restrict__ XT,
    const float* __restrict__ bias,
    short* __restrict__ qws, short* __restrict__ kws, short* __restrict__ vws)
{
    const int lBase = blockIdx.x * 128;
    const int oBase = blockIdx.y * 128;
    const int b     = blockIdx.z;
    const int tid   = threadIdx.x;
    const int wave  = tid >> 6;
    const int lane  = tid & 63;
    const int lid   = lane & 15;
    const int quad  = lane >> 4;
    const int rsub  = lane >> 3;
    const int cl    = (lane & 7) ^ rsub;

    __shared__ __align__(16) short Wt[128 * 64];
    __shared__ __align__(16) short Xt[128 * 64];

    const short* XTb = XT + (size_t)b * L * DIM;
    const int oLoc = (wave & 1) * 64;
    const int lLoc = (wave >> 1) * 64;

    f32x4 acc[4][4];
    #pragma unroll
    for (int mi = 0; mi < 4; ++mi)
        #pragma unroll
        for (int ni = 0; ni < 4; ++ni) acc[mi][ni] = (f32x4){0.f, 0.f, 0.f, 0.f};

    for (int c0 = 0; c0 < DIM; c0 += 64) {
        if (c0) __syncthreads();
        #pragma unroll
        for (int t = 0; t < 4; ++t) {
            const int ch = wave * 4 + t;
            const int r  = ch * 8 + rsub;
            gl_lds16(Wb  + (size_t)(oBase + r) * DIM + c0 + cl * 8, Wt + ch * 512);
            gl_lds16(XTb + (size_t)(lBase + r) * DIM + c0 + cl * 8, Xt + ch * 512);
        }
        __syncthreads();
        #pragma unroll
        for (int kc = 0; kc < 2; ++kc) {
            bf16x8 a[4], bb[4];
            #pragma unroll
            for (int mi = 0; mi < 4; ++mi)
                a[mi] = lds_frag(Wt, oLoc + mi * 16 + lid, kc * 4 + quad);
            #pragma unroll
            for (int ni = 0; ni < 4; ++ni)
                bb[ni] = lds_frag(Xt, lLoc + ni * 16 + lid, kc * 4 + quad);
            #pragma unroll
            for (int mi = 0; mi < 4; ++mi)
                #pragma unroll
                for (int ni = 0; ni < 4; ++ni)
                    acc[mi][ni] = __builtin_amdgcn_mfma_f32_16x16x32_bf16(
                        a[mi], bb[ni], acc[mi][ni], 0, 0, 0);
        }
    }

    const int rty = oBase >> 9;
    const float sc = (rty == 0) ? QSCALE : 1.0f;
    const int h = ((oBase + oLoc) >> 6) & 7;
    // sigma: swap bits 2 and 3 of the within-16 key index (involution)
    const int pl = (lid & 3) | ((lid & 4) << 1) | ((lid & 8) >> 1);

    #pragma unroll
    for (int mi = 0; mi < 4; ++mi) {
        const int dB = mi * 16 + quad * 4;
        float bia[4];
        #pragma unroll
        for (int r = 0; r < 4; ++r)
            bia[r] = bias[oBase + oLoc + mi * 16 + quad * 4 + r];

        if (rty < 2) {
            short* dst = (rty == 0 ? qws : kws) + (((size_t)b * NH + h) * L) * DH;
            #pragma unroll
            for (int ni = 0; ni < 4; ++ni) {
                const int l = lBase + lLoc + ni * 16 + lid;
                short4 pk = {f32_to_bf16s((acc[mi][ni][0] + bia[0]) * sc),
                             f32_to_bf16s((acc[mi][ni][1] + bia[1]) * sc),
                             f32_to_bf16s((acc[mi][ni][2] + bia[2]) * sc),
                             f32_to_bf16s((acc[mi][ni][3] + bia[3]) * sc)};
                *(short4*)(dst + (size_t)l * DH + dB) = pk;
            }
        } else {
            short* dst = vws + (((size_t)b * NH + h) * DH) * L;
            #pragma unroll
            for (int r = 0; r < 4; ++r) {
                const int d = dB + r;
                #pragma unroll
                for (int ni = 0; ni < 4; ++ni)
                    dst[(size_t)d * L + lBase + lLoc + ni * 16 + pl] =
                        f32_to_bf16s((acc[mi][ni][r] + bia[r]) * sc);
            }
        }
    }
}

// ---------------------------------------------------------------------------
// attn_mfma: 32x32x16 transposed-S attention, EXTERNAL split-j x4, XCD-local.
// R11: V pre-permuted (sigma) at qkv write -> PV A-frag is one swizzled b128;
// PV B-frag = own S^T C-layout dwords (no exchange); lsum via 4-op/dword VALU
// (no lacc MFMA, saves 4 MFMA/iter + 16 VGPRs).
// ---------------------------------------------------------------------------
__global__ __launch_bounds__(256) void attn_mfma(
    const short* __restrict__ Q, const short* __restrict__ K,
    const short* __restrict__ VT,
    short* __restrict__ Op0, short* __restrict__ Op1,
    short* __restrict__ Op2, short* __restrict__ Op3,
    float* __restrict__ Lp)
{
    const int h     = blockIdx.x >> 2;     // 0..7
    const int qtr   = blockIdx.x & 3;      // j-quarter
    const int b     = blockIdx.y;
    const int iTile = blockIdx.z;          // stride-128 linear id => same XCD
    const int tid   = threadIdx.x;
    const int wave  = tid >> 6;            // 0..3 (q-subtile)
    const int lane  = tid & 63;
    const int l5    = lane & 31;           // query col / A-frag row
    const int me    = lane >> 5;           // k-half within frags
    const int rsub  = lane >> 3;
    const int cl    = (lane & 7) ^ rsub;

    short* __restrict__ Op = (qtr & 2) ? ((qtr & 1) ? Op3 : Op2)
                                       : ((qtr & 1) ? Op1 : Op0);
    float* __restrict__ Lq = Lp + (size_t)qtr * (B * NH * L);

    const size_t headOff = ((size_t)b * NH + h) * (size_t)L * DH;
    const short* Qh = Q + headOff;    // [l][d]
    const short* Kh = K + headOff;    // [l][d]
    const short* Vh = VT + headOff;   // [d][l], sigma-permuted columns

    __shared__ __align__(16) short Kt[64 * 64];   // 8 KB, rows = key j
    __shared__ __align__(16) short Vt[64 * 64];   // 8 KB, rows = dim d

    // Q B-fragments (col n = query = l5, k = d = kc*16 + me*8 + i), in regs
    const int q0 = iTile * 128 + wave * 32;
    bf16x8 qf[4];
    #pragma unroll
    for (int kc = 0; kc < 4; ++kc)
        qf[kc] = *(const bf16x8*)(Qh + (size_t)(q0 + l5) * DH + kc * 16 + me * 8);

    f32x16 oacc[2];
    #pragma unroll
    for (int dt = 0; dt < 2; ++dt)
        #pragma unroll
        for (int r = 0; r < 16; ++r) oacc[dt][r] = 0.f;
    float lsum = 0.f;

    const int jt0 = qtr * 8;
    for (int it = 0; it < 8; ++it) {
        const int j0 = (jt0 + it) * 64;
        if (it) __syncthreads();
        #pragma unroll
        for (int t = 0; t < 2; ++t) {
            const int ch = wave * 2 + t;
            const int r  = ch * 8 + rsub;
            gl_lds16(Kh + (size_t)(j0 + r) * DH + cl * 8, Kt + ch * 512);
            gl_lds16(Vh + (size_t)r * L + j0 + cl * 8,    Vt + ch * 512);
        }
        __syncthreads();

        // ---- per 32-key m-tile: S^T, exp2 + perm-pack -> dw (C-layout dwords)
        // dw[mt][g][p] packs S^T regs (4g+2p, 4g+2p+1): local j = 8g+4me+2p(+1)
        unsigned dw[2][4][2];
        #pragma unroll
        for (int mt = 0; mt < 2; ++mt) {
            f32x16 s;
            #pragma unroll
            for (int r = 0; r < 16; ++r) s[r] = 0.f;
            #pragma unroll
            for (int kc = 0; kc < 4; ++kc) {
                bf16x8 a = lds_frag(Kt, mt * 32 + l5, kc * 2 + me);
                s = __builtin_amdgcn_mfma_f32_32x32x16_bf16(a, qf[kc], s, 0, 0, 0);
            }
            #pragma unroll
            for (int g = 0; g < 4; ++g) {
                #pragma unroll
                for (int p = 0; p < 2; ++p) {
                    const float p0 = fast_exp2(s[4 * g + 2 * p]);
                    const float p1 = fast_exp2(s[4 * g + 2 * p + 1]);
                    const unsigned pk = __builtin_amdgcn_perm(
                        __float_as_uint(p1), __float_as_uint(p0), 0x07060302u);
                    lsum += __uint_as_float(pk << 16);          // trunc p0
                    lsum += __uint_as_float(pk & 0xffff0000u);  // trunc p1
                    dw[mt][g][p] = pk;
                }
            }
        }

        // ---- PV: B-frag = own dwords (sigma k-order); A-frag = one b128 of
        // the pre-permuted V tile at chunk (mt*2+kl)*2+me.
        #pragma unroll
        for (int mt = 0; mt < 2; ++mt) {
            #pragma unroll
            for (int kl = 0; kl < 2; ++kl) {
                i32x4 bi = {(int)dw[mt][2 * kl][0], (int)dw[mt][2 * kl][1],
                            (int)dw[mt][2 * kl + 1][0], (int)dw[mt][2 * kl + 1][1]};
                bf16x8 pb = __builtin_bit_cast(bf16x8, bi);
                const int ch = (mt * 2 + kl) * 2 + me;
                #pragma unroll
                for (int dt = 0; dt < 2; ++dt) {
                    bf16x8 a = lds_frag(Vt, dt * 32 + l5, ch);
                    oacc[dt] = __builtin_amdgcn_mfma_f32_32x32x16_bf16(a, pb, oacc[dt], 0, 0, 0);
                }
            }
        }
    }

    // ---- partial sum-exp: lane and lane^32 hold complementary j-halves
    const float vh = lsum + __shfl_xor(lsum, 32);
    const int qg = q0 + l5;
    if (me == 0)
        Lq[((size_t)b * NH + h) * L + qg] = vh;

    // ---- normalized partial o_p = O_p / l_p -> bf16 [b][l][h*64+d]
    const float inv = 1.0f / vh;
    short* ab = Op + ((size_t)b * L + qg) * HID + h * DH;
    #pragma unroll
    for (int dt = 0; dt < 2; ++dt) {
        #pragma unroll
        for (int g = 0; g < 4; ++g) {
            const int d = dt * 32 + 8 * g + me * 4;
            short4 pk = {f32_to_bf16s(oacc[dt][4 * g]     * inv),
                         f32_to_bf16s(oacc[dt][4 * g + 1] * inv),
                         f32_to_bf16s(oacc[dt][4 * g + 2] * inv),
                         f32_to_bf16s(oacc[dt][4 * g + 3] * inv)};
            *(short4*)(ab + d) = pk;
        }
    }
}

// ---------------------------------------------------------------------------
// combine4: Abf[b][l][c] = sum_i(l_i * o_i) / sum_i(l_i), bf16 out.
// ---------------------------------------------------------------------------
__global__ __launch_bounds__(256) void combine4(
    const short* __restrict__ O0, const short* __restrict__ O1,
    const short* __restrict__ O2, const short* __restrict__ O3,
    const float* __restrict__ Lp, short* __restrict__ Abf)
{
    const int g = blockIdx.x * 256 + threadIdx.x;
    const int i = g * 4;
    const int b = i >> 20;
    const int rem = i & 1048575;
    const int l = rem >> 9;
    const int c = rem & 511;
    const int h = c >> 6;
    const size_t li = ((size_t)b * NH + h) * L + l;
    const float w0 = Lp[li];
    const float w1 = Lp[li + (size_t)B * NH * L];
    const float w2 = Lp[li + (size_t)2 * B * NH * L];
    const float w3 = Lp[li + (size_t)3 * B * NH * L];
    const float inv = 1.0f / (w0 + w1 + w2 + w3);
    const short4 a = *(const short4*)(O0 + i);
    const short4 bb = *(const short4*)(O1 + i);
    const short4 cc = *(const short4*)(O2 + i);
    const short4 dd = *(const short4*)(O3 + i);
    short4 pk = {
        f32_to_bf16s((w0 * bf16s_to_f32(a.x) + w1 * bf16s_to_f32(bb.x) +
                      w2 * bf16s_to_f32(cc.x) + w3 * bf16s_to_f32(dd.x)) * inv),
        f32_to_bf16s((w0 * bf16s_to_f32(a.y) + w1 * bf16s_to_f32(bb.y) +
                      w2 * bf16s_to_f32(cc.y) + w3 * bf16s_to_f32(dd.y)) * inv),
        f32_to_bf16s((w0 * bf16s_to_f32(a.z) + w1 * bf16s_to_f32(bb.z) +
                      w2 * bf16s_to_f32(cc.z) + w3 * bf16s_to_f32(dd.z)) * inv),
        f32_to_bf16s((w0 * bf16s_to_f32(a.w) + w1 * bf16s_to_f32(bb.w) +
                      w2 * bf16s_to_f32(cc.w) + w3 * bf16s_to_f32(dd.w)) * inv)};
    *(short4*)(Abf + i) = pk;
}

// ---------------------------------------------------------------------------
// out_mfma: 64o x 128l tile, BK=64, LDS-staged.
// ---------------------------------------------------------------------------
__global__ __launch_bounds__(256) void out_mfma(
    const short* __restrict__ Wo, const short* __restrict__ Abf,
    const float* __restrict__ bias, float* __restrict__ out)
{
    const int lBase = blockIdx.x * 128;
    const int oBase = blockIdx.y * 64;
    const int b     = blockIdx.z;
    const int tid   = threadIdx.x;
    const int wave  = tid >> 6;
    const int lane  = tid & 63;
    const int lid   = lane & 15;
    const int quad  = lane >> 4;
    const int rsub  = lane >> 3;
    const int cl    = (lane & 7) ^ rsub;

    __shared__ __align__(16) short Wt[64 * 64];
    __shared__ __align__(16) short At[128 * 64];

    const short* Ab = Abf + (size_t)b * L * HID;
    const int oLoc = (wave & 1) * 32;
    const int lLoc = (wave >> 1) * 64;

    f32x4 acc[2][4];
    #pragma unroll
    for (int mi = 0; mi < 2; ++mi)
        #pragma unroll
        for (int ni = 0; ni < 4; ++ni) acc[mi][ni] = (f32x4){0.f, 0.f, 0.f, 0.f};

    for (int c0 = 0; c0 < HID; c0 += 64) {
        if (c0) __syncthreads();
        #pragma unroll
        for (int t = 0; t < 2; ++t) {
            const int ch = wave * 2 + t;
            const int r  = ch * 8 + rsub;
            gl_lds16(Wo + (size_t)(oBase + r) * HID + c0 + cl * 8, Wt + ch * 512);
        }
        #pragma unroll
        for (int t = 0; t < 4; ++t) {
            const int ch = wave * 4 + t;
            const int r  = ch * 8 + rsub;
            gl_lds16(Ab + (size_t)(lBase + r) * HID + c0 + cl * 8, At + ch * 512);
        }
        __syncthreads();
        #pragma unroll
        for (int kc = 0; kc < 2; ++kc) {
            bf16x8 a[2], bb[4];
            #pragma unroll
            for (int mi = 0; mi < 2; ++mi)
                a[mi] = lds_frag(Wt, oLoc + mi * 16 + lid, kc * 4 + quad);
            #pragma unroll
            for (int ni = 0; ni < 4; ++ni)
                bb[ni] = lds_frag(At, lLoc + ni * 16 + lid, kc * 4 + quad);
            #pragma unroll
            for (int mi = 0; mi < 2; ++mi)
                #pragma unroll
                for (int ni = 0; ni < 4; ++ni)
                    acc[mi][ni] = __builtin_amdgcn_mfma_f32_16x16x32_bf16(
                        a[mi], bb[ni], acc[mi][ni], 0, 0, 0);
        }
    }

    #pragma unroll
    for (int mi = 0; mi < 2; ++mi) {
        #pragma unroll
        for (int r = 0; r < 4; ++r) {
            const int o = oBase + oLoc + mi * 16 + quad * 4 + r;
            const float bia = bias[o];
            #pragma unroll
            for (int ni = 0; ni < 4; ++ni)
                out[((size_t)b * DIM + o) * L + lBase + lLoc + ni * 16 + lid] =
                    acc[mi][ni][r] + bia;
        }
    }
}

// ---------------------------------------------------------------------------
extern "C" void kernel_launch(void* const* d_in, const int* in_sizes, int n_in,
                              void* d_out, int out_size, void* d_ws, size_t ws_size,
                              hipStream_t stream)
{
    const float* x     = (const float*)d_in[0];
    const float* w_qkv = (const float*)d_in[1];
    const float* b_qkv = (const float*)d_in[2];
    const float* w_out = (const float*)d_in[3];
    const float* b_out = (const float*)d_in[4];
    float* out = (float*)d_out;

    char* w = (char*)d_ws;
    short* xT  = (short*)(w);                    //  8 MB  bf16 [b][l][c]  (dead after qkv)
    short* wqb = (short*)(w + (8u << 20));       //  1.5 MB
    short* wob = wqb + 786432;                   //  0.5 MB
    short* qws = (short*)(w + (10u << 20));      //  8 MB  [b][h][l][d]
    short* kws = (short*)(w + (18u << 20));      //  8 MB  [b][h][l][d]
    short* vws = (short*)(w + (26u << 20));      //  8 MB  [b][h][d][l] sigma-perm
    short* Abf = (short*)(w + (34u << 20));      //  8 MB  [b][l][hid]
    short* Op1 = (short*)(w);                    //  8 MB  (reuses dead xT)
    short* Op2 = (short*)(w + (42u << 20));      //  8 MB
    short* Op3 = (short*)(w + (50u << 20));      //  8 MB
    float* Lp  = (float*)(w + (58u << 20));      //  1 MB  (4 x [b][h][l])
    short* Op0 = (short*)d_out;                  //  8 MB of d_out (scratch)

    dim3 blk(256);
    prep<<<dim3(2048), blk, 0, stream>>>(w_qkv, w_out, wqb, x, xT);
    qkv_mfma<<<dim3(L / 128, 1536 / 128, B), blk, 0, stream>>>(
        wqb, xT, b_qkv, qws, kws, vws);
    attn_mfma<<<dim3(NH * 4, B, L / 128), blk, 0, stream>>>(
        qws, kws, vws, Op0, Op1, Op2, Op3, Lp);
    combine4<<<dim3(4096), blk, 0, stream>>>(Op0, Op1, Op2, Op3, Lp, Abf);
    out_mfma<<<dim3(L / 128, DIM / 64, B), blk, 0, stream>>>(
        wob, Abf, b_out, out);
}